// Round 11
// baseline (7040.523 us; speedup 1.0000x reference)
//
#include <hip/hip_runtime.h>
#include <cstdint>

#define B_  128
#define T_  1024
#define DIN 13
#define HS  256
#define N0  77
#define N1  51
#define N2  128

// zg layout (f16 elems, 272 = 34 quads):
//   e0..12 x (13..15 pad) | e16..143 l2o | e144..194 l1o | e195..271 l0o
#define QG   34
#define NRG  1024
#define Q0   12
#define NR0  308
#define Q1   16
#define NR1  204
#define Q2   23
#define NR2  512
#define Q2LDS 18

#define NPAIR 64          // G=2: 64 pairs x 2 elements

typedef _Float16 h2_t __attribute__((ext_vector_type(2)));

static __device__ __forceinline__ uint32_t pk2(float a, float b) {
  h2_t v; v.x = (_Float16)a; v.y = (_Float16)b;
  return __builtin_bit_cast(uint32_t, v);
}
static __device__ __forceinline__ unsigned short f16b(float v) {
  return __builtin_bit_cast(unsigned short, (_Float16)v);
}
static __device__ __forceinline__ void st16(void* base, int idx, unsigned short v) {
  ((unsigned short*)base)[idx] = v;
}
static __device__ __forceinline__ float dot2f(uint32_t w, uint32_t z, float acc) {
#if __has_builtin(__builtin_amdgcn_fdot2)
  return __builtin_amdgcn_fdot2(__builtin_bit_cast(h2_t, w), __builtin_bit_cast(h2_t, z), acc, false);
#else
  h2_t a = __builtin_bit_cast(h2_t, w), b = __builtin_bit_cast(h2_t, z);
  return acc + (float)a.x * (float)b.x + (float)a.y * (float)b.y;
#endif
}
static __device__ __forceinline__ float dot8f(uint4 w, uint4 z, float acc) {
  acc = dot2f(w.x, z.x, acc);
  acc = dot2f(w.y, z.y, acc);
  acc = dot2f(w.z, z.z, acc);
  acc = dot2f(w.w, z.w, acc);
  return acc;
}
static __device__ __forceinline__ float sigf(float x) { return 1.f / (1.f + expf(-x)); }

// tagged-word exchange: relaxed agent-scope atomics (coherent, no L2 invalidation).
static __device__ __forceinline__ void axpub(int* p, int tag, unsigned short v16) {
  __hip_atomic_store(p, (tag << 16) | (int)v16, __ATOMIC_RELAXED, __HIP_MEMORY_SCOPE_AGENT);
}
static __device__ __forceinline__ unsigned short axpoll(const int* p, int tag) {
  int w;
  do {
    w = __hip_atomic_load((int*)p, __ATOMIC_RELAXED, __HIP_MEMORY_SCOPE_AGENT);
  } while (((unsigned)w >> 16) != (unsigned)tag);
  return (unsigned short)(w & 0xFFFF);
}

// ---------------- prep kernels ----------------

__global__ void prep_gates3(const float* __restrict__ Wih, const float* __restrict__ Whh,
                            uint32_t* __restrict__ out) {
  int id = blockIdx.x * blockDim.x + threadIdx.x;
  if (id >= 136 * NRG) return;
  int k2 = id >> 10, row = id & (NRG - 1);
  float v[2];
#pragma unroll
  for (int j = 0; j < 2; ++j) {
    int e = 2 * k2 + j;
    float val = 0.f;
    if (e < 13) val = Wih[row * DIN + e];
    else if (e >= 16 && e < 144) val = Whh[row * HS + 128 + (e - 16)];
    else if (e >= 144 && e < 195) val = Whh[row * HS + 77 + (e - 144)];
    else if (e >= 195 && e < 272) val = Whh[row * HS + (e - 195)];
    v[j] = val;
  }
  out[((k2 >> 2) * NRG + row) * 4 + (k2 & 3)] = pk2(v[0], v[1]);
}

__global__ void prep_cfc2(const float* __restrict__ Wf1, const float* __restrict__ Wf2,
                          const float* __restrict__ Wta, const float* __restrict__ Wtb,
                          const float* __restrict__ mask,
                          int nh, int K, int NR, int K2,
                          int p0n, int p0c, int p1s, int p1n, int p1c,
                          uint32_t* __restrict__ out) {
  int id = blockIdx.x * blockDim.x + threadIdx.x;
  if (id >= NR * K2) return;
  int k2 = id / NR, r = id % NR;
  int mat = r / nh, o = r % nh;
  const float* W = (mat == 0) ? Wf1 : (mat == 1) ? Wf2 : (mat == 2) ? Wta : Wtb;
  float v[2];
#pragma unroll
  for (int j = 0; j < 2; ++j) {
    int e = 2 * k2 + j;
    int col = -1;
    if (e < p0n) col = p0c + e;
    else if (e >= p1s && e < p1s + p1n) col = p1c + (e - p1s);
    float val = 0.f;
    if (col >= 0) {
      val = W[o * K + col];
      if (mat < 2) val *= mask[o * K + col];
    }
    v[j] = val;
  }
  out[((k2 >> 2) * NR + r) * 4 + (k2 & 3)] = pk2(v[0], v[1]);
}

// ---------------- shared structs ----------------

struct SMA2 {
  uint4 l0w[Q0 * NR0];     // 59136
  uint4 l1w[Q1 * NR1];     // 52224
  uint4 zb[2][2][QG];      // 2176
  uint4 z0[2][Q0];         // 384
  uint4 z1[2][Q1];         // 512
  float garr[2][512];      // 4096
  float ffb[2][NR0];       // 2464
  float cb0[NR0];          // 1232
  float cb1[NR1];          // 816
};
struct SMB2 {
  uint4 l2w[Q2LDS * NR2];  // 147456
  uint4 zb[2][2][QG];      // 2176
  uint4 z2[2][Q2];         // 736
  float garr[2][512];      // 4096
  float ffb[2][NR2];       // 4096
  float cb2[NR2];          // 2048
  uint4 hwq[12][16];       // 3072
  float hb[12];            // 48
};
static_assert(sizeof(SMA2) <= 163840, "SMA2 too big");
static_assert(sizeof(SMB2) <= 163840, "SMB2 too big");

struct SMA {
  uint4 l0w[Q0 * NR0];
  uint4 l1w[Q1 * NR1];
  uint4 zb[2][QG];
  uint4 z0[Q0];
  uint4 z1[Q1];
  float garr[512];
  float ffb[NR0];
  float cb0[NR0];
  float cb1[NR1];
};
struct SMB {
  uint4 l2w[Q2LDS * NR2];
  uint4 zb[2][QG];
  uint4 z2[Q2];
  float garr[512];
  float ffb[NR2];
  float cb2[NR2];
  uint4 hwq[12][16];
  float hb[12];
};

struct PArgs {
  const float* x;
  const float* bih; const float* bhh;
  const float* b0[4]; const float* b1[4]; const float* b2[4];
  const float* gW; const float* gb; const float* aW; const float* ab;
  const float* uW; const float* ub;
  const uint4* wsG; const uint4* wsL0; const uint4* wsL1; const uint4* wsL2;
  int* ex;
  float* out;
};

// ======== G=2 kernel: 64 pairs, each serving 2 batch elements ========
// Round-10's version spilled (unroll-8 double-acc loops ~116 live VGPRs at the
// 128 cap). This version caps every streamed loop at unroll 4 (~80 live) and
// keeps head-accumulator live ranges out of the gate loop.
__global__ __launch_bounds__(512, 2) void rnn_g2(PArgs P) {
  extern __shared__ char smraw[];
  const int tid = threadIdx.x;
  const bool isA = (blockIdx.x < NPAIR);
  const int pr = blockIdx.x & (NPAIR - 1);
  int* EX = P.ex + pr * 512;                 // el0: [0..255], el1: [256..511]
  const float* xb0 = P.x + (size_t)(2 * pr) * T_ * DIN;
  const float* xb1 = xb0 + (size_t)T_ * DIN;
  const size_t UNC_OFF = (size_t)B_ * T_ * 6;

  if (isA) {
    SMA2& sm = *(SMA2*)smraw;
    for (int i = tid; i < Q0 * NR0; i += 512) sm.l0w[i] = P.wsL0[i];
    for (int i = tid; i < Q1 * NR1; i += 512) sm.l1w[i] = P.wsL1[i];
    for (int i = tid; i < NR0; i += 512) sm.cb0[i] = P.b0[i / N0][i % N0];
    for (int i = tid; i < NR1; i += 512) sm.cb1[i] = P.b1[i / N1][i % N1];
    {
      uint32_t* zz = (uint32_t*)sm.zb;
      for (int i = tid; i < (4 * QG + 2 * Q0 + 2 * Q1) * 4; i += 512) zz[i] = 0u;
    }
    const int grow = ((tid >> 7) << 8) | (tid & 127);   // units 0..127
    const float bg = P.bih[grow] + P.bhh[grow];
    float c_r = 0.f;
    __syncthreads();
    if (tid < 26) {
      int e = tid >= 13, i = tid - 13 * e;
      st16(sm.zb[0][e], i, f16b(e ? xb1[i] : xb0[i]));
    }
    __syncthreads();
    {
      float a0 = bg, a1 = bg;
#pragma unroll
      for (int q = 0; q < 2; ++q) {
        uint4 w = P.wsG[q * NRG + grow];
        a0 = dot8f(w, sm.zb[0][0][q], a0);
        a1 = dot8f(w, sm.zb[0][1][q], a1);
      }
      sm.garr[0][tid] = a0;
      sm.garr[1][tid] = a1;
    }
    __syncthreads();
    int cur = 0;

    for (int t = 0; t < T_; ++t) {
      const int nxt = cur ^ 1;
      // P1: LSTM both els + x(t+1) prefetch + x(t)->z0 copy
      if (tid < 256) {
        int e = tid >> 7, u = tid & 127;
        float gi = sm.garr[e][u], gf = sm.garr[e][128 + u];
        float gg = sm.garr[e][256 + u], go = sm.garr[e][384 + u];
        float cn = sigf(gf) * c_r + sigf(gi) * tanhf(gg);
        c_r = cn;
        float h = sigf(go) * tanhf(cn);
        if (u < N0) st16(sm.z0[e], 13 + u, f16b(h));
        else        st16(sm.z1[e], u - N0, f16b(h));
      } else if (tid >= 320 && tid < 352) {
        int j = tid - 320, e = j >> 4, i = j & 15;
        if (i < 13) {
          const float* xe = e ? xb1 : xb0;
          float xv = (t + 1 < T_) ? xe[(size_t)(t + 1) * DIN + i] : 0.f;
          st16(sm.zb[nxt][e], i, f16b(xv));
        }
      } else if (tid >= 352 && tid < 384) {
        int j = tid - 352, e = j >> 4, i = j & 15;
        if (i < 13) st16(sm.z0[e], i, ((unsigned short*)sm.zb[cur][e])[i]);
      }
      __syncthreads();
      // P2: l0 matvec (shared weights, 2 accs)
      if (tid < NR0) {
        float a0 = sm.cb0[tid], a1 = a0;
#pragma unroll 4
        for (int q = 0; q < Q0; ++q) {
          uint4 w = sm.l0w[q * NR0 + tid];
          a0 = dot8f(w, sm.z0[0][q], a0);
          a1 = dot8f(w, sm.z0[1][q], a1);
        }
        bool tn = (tid < 2 * N0);
        sm.ffb[0][tid] = tn ? tanhf(a0) : a0;
        sm.ffb[1][tid] = tn ? tanhf(a1) : a1;
      }
      __syncthreads();
      // P3: combine l0 -> publish tagged (both els)
      if (tid < 2 * N0) {
        int e = tid >= N0, o = tid - N0 * e;
        float ti = sigf(sm.ffb[e][2 * N0 + o] + sm.ffb[e][3 * N0 + o]);
        float v = sm.ffb[e][o] * (1.f - ti) + ti * sm.ffb[e][N0 + o];
        unsigned short v16 = f16b(v);
        axpub(EX + e * 256 + o, t + 1, v16);
        st16(sm.z1[e], 51 + o, v16);
        st16(sm.zb[nxt][e], 195 + o, v16);
      }
      __syncthreads();
      // P4: l1 matvec
      if (tid < NR1) {
        float a0 = sm.cb1[tid], a1 = a0;
#pragma unroll 4
        for (int q = 0; q < Q1; ++q) {
          uint4 w = sm.l1w[q * NR1 + tid];
          a0 = dot8f(w, sm.z1[0][q], a0);
          a1 = dot8f(w, sm.z1[1][q], a1);
        }
        bool tn = (tid < 2 * N1);
        sm.ffb[0][tid] = tn ? tanhf(a0) : a0;
        sm.ffb[1][tid] = tn ? tanhf(a1) : a1;
      }
      __syncthreads();
      // P5: combine l1 -> publish
      if (tid < 2 * N1) {
        int e = tid >= N1, o = tid - N1 * e;
        float ti = sigf(sm.ffb[e][2 * N1 + o] + sm.ffb[e][3 * N1 + o]);
        float v = sm.ffb[e][o] * (1.f - ti) + ti * sm.ffb[e][N1 + o];
        unsigned short v16 = f16b(v);
        axpub(EX + e * 256 + N0 + o, t + 1, v16);
        st16(sm.zb[nxt][e], 144 + o, v16);
      }
      __syncthreads();
      // P6: gates(t+1) partial (x + l1o + l0o quads)
      float a0 = bg, a1 = bg;
#pragma unroll
      for (int q = 0; q < 2; ++q) {
        uint4 w = P.wsG[q * NRG + grow];
        a0 = dot8f(w, sm.zb[nxt][0][q], a0);
        a1 = dot8f(w, sm.zb[nxt][1][q], a1);
      }
#pragma unroll 4
      for (int q = 18; q < 34; ++q) {
        uint4 w = P.wsG[q * NRG + grow];
        a0 = dot8f(w, sm.zb[nxt][0][q], a0);
        a1 = dot8f(w, sm.zb[nxt][1][q], a1);
      }
      // P7: poll hop2 (l2o, both els)
      if (tid < 256) {
        int e = tid >> 7, j = tid & 127;
        unsigned short v16 = axpoll(EX + e * 256 + 128 + j, t + 1);
        st16(sm.zb[nxt][e], 16 + j, v16);
      }
      __syncthreads();
      // P8: finish gates(t+1) (l2o quads)
#pragma unroll 4
      for (int q = 2; q < 18; ++q) {
        uint4 w = P.wsG[q * NRG + grow];
        a0 = dot8f(w, sm.zb[nxt][0][q], a0);
        a1 = dot8f(w, sm.zb[nxt][1][q], a1);
      }
      sm.garr[0][tid] = a0;
      sm.garr[1][tid] = a1;
      __syncthreads();
      cur = nxt;
    }
  } else {
    // ======== role B: LSTM[128:256] + full l2 + heads, 2 els ========
    SMB2& sm = *(SMB2*)smraw;
    for (int i = tid; i < Q2LDS * NR2; i += 512) sm.l2w[i] = P.wsL2[i];
    for (int i = tid; i < NR2; i += 512) sm.cb2[i] = P.b2[i >> 7][i & 127];
    for (int i = tid; i < 768; i += 512) {
      int r = i >> 6, w = i & 63;
      const float* W = (r < 3) ? P.gW + r * 128 : (r < 6) ? P.aW + (r - 3) * 128 : P.uW + (r - 6) * 128;
      ((uint32_t*)sm.hwq)[i] = pk2(W[2 * w], W[2 * w + 1]);
    }
    if (tid < 12) sm.hb[tid] = (tid < 3) ? P.gb[tid] : (tid < 6) ? P.ab[tid - 3] : P.ub[tid - 6];
    {
      uint32_t* zz = (uint32_t*)sm.zb;
      for (int i = tid; i < (4 * QG + 2 * Q2) * 4; i += 512) zz[i] = 0u;
    }
    const int grow = ((tid >> 7) << 8) | 128 | (tid & 127);   // units 128..255
    const float bg = P.bih[grow] + P.bhh[grow];
    float c_r = 0.f;
    __syncthreads();
    if (tid < 26) {
      int e = tid >= 13, i = tid - 13 * e;
      st16(sm.zb[0][e], i, f16b(e ? xb1[i] : xb0[i]));
    }
    __syncthreads();
    int cur = 0;

    for (int t = 0; t < T_; ++t) {
      const int nxt = cur ^ 1;
      // Q1a: heads(t-1) first (keeps head acc live range outside gate loop)
      if (tid < 24 && t > 0) {
        int e = tid >= 12, r = tid - 12 * e;
        float a = sm.hb[r];
#pragma unroll 4
        for (int q = 0; q < 16; ++q) a = dot8f(sm.hwq[r][q], sm.zb[cur][e][2 + q], a);
        size_t base = ((size_t)(2 * pr + e) * T_ + (t - 1)) * 6;
        if (r < 6) P.out[base + r] = a;
        else {
          float sp = (a > 0.f) ? (a + log1pf(expf(-a))) : log1pf(expf(a));
          P.out[UNC_OFF + base + (r - 6)] = sp;
        }
      }
      // Q1b: full gates(t) both els, two sequential halves (caps live regs)
      float a0 = bg, a1 = bg;
#pragma unroll 4
      for (int q = 0; q < 17; ++q) {
        uint4 w = P.wsG[q * NRG + grow];
        a0 = dot8f(w, sm.zb[cur][0][q], a0);
        a1 = dot8f(w, sm.zb[cur][1][q], a1);
      }
#pragma unroll 4
      for (int q = 17; q < QG; ++q) {
        uint4 w = P.wsG[q * NRG + grow];
        a0 = dot8f(w, sm.zb[cur][0][q], a0);
        a1 = dot8f(w, sm.zb[cur][1][q], a1);
      }
      sm.garr[0][tid] = a0;
      sm.garr[1][tid] = a1;
      __syncthreads();
      // Q2: LSTM both els -> z2 h-part; x(t+1) -> zb[nxt]
      if (tid < 256) {
        int e = tid >> 7, u = tid & 127;
        float gi = sm.garr[e][u], gf = sm.garr[e][128 + u];
        float gg = sm.garr[e][256 + u], go = sm.garr[e][384 + u];
        float cn = sigf(gf) * c_r + sigf(gi) * tanhf(gg);
        c_r = cn;
        float h = sigf(go) * tanhf(cn);
        st16(sm.z2[e], 56 + u, f16b(h));
      } else if (tid >= 320 && tid < 352) {
        int j = tid - 320, e = j >> 4, i = j & 15;
        if (i < 13) {
          const float* xe = e ? xb1 : xb0;
          float xv = (t + 1 < T_) ? xe[(size_t)(t + 1) * DIN + i] : 0.f;
          st16(sm.zb[nxt][e], i, f16b(xv));
        }
      }
      __syncthreads();
      // Q3: l2 partial over h2 quads (7..17 LDS, 18..22 streamed)
      float b0a = sm.cb2[tid], b1a = b0a;
#pragma unroll 4
      for (int q = 7; q < Q2LDS; ++q) {
        uint4 w = sm.l2w[q * NR2 + tid];
        b0a = dot8f(w, sm.z2[0][q], b0a);
        b1a = dot8f(w, sm.z2[1][q], b1a);
      }
#pragma unroll 2
      for (int q = Q2LDS; q < Q2; ++q) {
        uint4 w = P.wsL2[q * NR2 + tid];
        b0a = dot8f(w, sm.z2[0][q], b0a);
        b1a = dot8f(w, sm.z2[1][q], b1a);
      }
      // Q4: poll hop1 {l0o, l1o} both els
      if (tid < 256) {
        int e = tid >> 7, j = tid & 127;
        unsigned short v16 = axpoll(EX + e * 256 + j, t + 1);
        if (j < N0) {
          st16(sm.zb[nxt][e], 195 + j, v16);
        } else {
          int o = j - N0;
          st16(sm.z2[e], o, v16);
          st16(sm.zb[nxt][e], 144 + o, v16);
        }
      }
      __syncthreads();
      // Q5: finish l2 (l1o quads 0..6, LDS)
#pragma unroll 4
      for (int q = 0; q < 7; ++q) {
        uint4 w = sm.l2w[q * NR2 + tid];
        b0a = dot8f(w, sm.z2[0][q], b0a);
        b1a = dot8f(w, sm.z2[1][q], b1a);
      }
      {
        bool tn = (tid < 2 * N2);
        sm.ffb[0][tid] = tn ? tanhf(b0a) : b0a;
        sm.ffb[1][tid] = tn ? tanhf(b1a) : b1a;
      }
      __syncthreads();
      // Q6: combine l2 -> publish hop2 (both els)
      if (tid < 256) {
        int e = tid >> 7, u = tid & 127;
        float ti = sigf(sm.ffb[e][2 * N2 + u] + sm.ffb[e][3 * N2 + u]);
        float v = sm.ffb[e][u] * (1.f - ti) + ti * sm.ffb[e][N2 + u];
        unsigned short v16 = f16b(v);
        axpub(EX + e * 256 + 128 + u, t + 1, v16);
        st16(sm.zb[nxt][e], 16 + u, v16);
      }
      __syncthreads();
      cur = nxt;
    }
    // tail: heads for t = T_-1
    if (tid < 24) {
      int e = tid >= 12, r = tid - 12 * e;
      float a = sm.hb[r];
#pragma unroll 4
      for (int q = 0; q < 16; ++q) a = dot8f(sm.hwq[r][q], sm.zb[cur][e][2 + q], a);
      size_t base = ((size_t)(2 * pr + e) * T_ + (T_ - 1)) * 6;
      if (r < 6) P.out[base + r] = a;
      else {
        float sp = (a > 0.f) ? (a + log1pf(expf(-a))) : log1pf(expf(a));
        P.out[UNC_OFF + base + (r - 6)] = sp;
      }
    }
  }
}

// ======== coop3 fallback (round-7 kernel verbatim; 96 VGPR, ~5.15 ms) ========
__global__ __launch_bounds__(512, 2) void rnn_coop3(PArgs P) {
  extern __shared__ char smraw[];
  const int tid = threadIdx.x;
  const bool isA = (blockIdx.x < B_);
  const int b = blockIdx.x & (B_ - 1);
  int* EX = P.ex + b * 256;
  const float* xb = P.x + (size_t)b * T_ * DIN;
  const size_t UNC_OFF = (size_t)B_ * T_ * 6;

  if (isA) {
    SMA& sm = *(SMA*)smraw;
    for (int i = tid; i < Q0 * NR0; i += 512) sm.l0w[i] = P.wsL0[i];
    for (int i = tid; i < Q1 * NR1; i += 512) sm.l1w[i] = P.wsL1[i];
    for (int i = tid; i < NR0; i += 512) sm.cb0[i] = P.b0[i / N0][i % N0];
    for (int i = tid; i < NR1; i += 512) sm.cb1[i] = P.b1[i / N1][i % N1];
    {
      uint32_t* zz = (uint32_t*)sm.zb;
      for (int i = tid; i < (2 * QG + Q0 + Q1) * 4; i += 512) zz[i] = 0u;
    }
    const int grow = ((tid >> 7) << 8) | (tid & 127);
    const float bg = P.bih[grow] + P.bhh[grow];
    float c_r = 0.f;
    __syncthreads();
    if (tid < 13) st16(sm.zb[0], tid, f16b(xb[tid]));
    __syncthreads();
    uint4* zbc = sm.zb[0];
    uint4* zbn = sm.zb[1];
    {
      float acc = bg;
      acc = dot8f(P.wsG[0 * NRG + grow], zbc[0], acc);
      acc = dot8f(P.wsG[1 * NRG + grow], zbc[1], acc);
      sm.garr[tid] = acc;
    }
    __syncthreads();

    for (int t = 0; t < T_; ++t) {
      if (tid < 128) {
        float gi = sm.garr[tid], gf = sm.garr[128 + tid];
        float gg = sm.garr[256 + tid], go = sm.garr[384 + tid];
        float cn = sigf(gf) * c_r + sigf(gi) * tanhf(gg);
        c_r = cn;
        float h = sigf(go) * tanhf(cn);
        if (tid < N0) st16(sm.z0, 13 + tid, f16b(h));
        else          st16(sm.z1, tid - N0, f16b(h));
      } else if (tid >= 320 && tid < 336) {
        int i = tid - 320;
        if (i < 13) {
          float xv = (t + 1 < T_) ? xb[(size_t)(t + 1) * DIN + i] : 0.f;
          st16(zbn, i, f16b(xv));
        }
      } else if (tid >= 336 && tid < 352) {
        int i = tid - 336;
        if (i < 13) st16(sm.z0, i, ((unsigned short*)zbc)[i]);
      }
      __syncthreads();
      if (tid < NR0) {
        float a = sm.cb0[tid];
#pragma unroll
        for (int q = 0; q < Q0; ++q) a = dot8f(sm.l0w[q * NR0 + tid], sm.z0[q], a);
        sm.ffb[tid] = (tid < 2 * N0) ? tanhf(a) : a;
      }
      __syncthreads();
      if (tid < N0) {
        float ti = sigf(sm.ffb[2 * N0 + tid] + sm.ffb[3 * N0 + tid]);
        float v = sm.ffb[tid] * (1.f - ti) + ti * sm.ffb[N0 + tid];
        unsigned short v16 = f16b(v);
        axpub(EX + tid, t + 1, v16);
        st16(sm.z1, 51 + tid, v16);
        st16(zbn, 195 + tid, v16);
      }
      __syncthreads();
      if (tid < NR1) {
        float a = sm.cb1[tid];
#pragma unroll
        for (int q = 0; q < Q1; ++q) a = dot8f(sm.l1w[q * NR1 + tid], sm.z1[q], a);
        sm.ffb[tid] = (tid < 2 * N1) ? tanhf(a) : a;
      }
      __syncthreads();
      if (tid < N1) {
        float ti = sigf(sm.ffb[2 * N1 + tid] + sm.ffb[3 * N1 + tid]);
        float v = sm.ffb[tid] * (1.f - ti) + ti * sm.ffb[N1 + tid];
        unsigned short v16 = f16b(v);
        axpub(EX + N0 + tid, t + 1, v16);
        st16(zbn, 144 + tid, v16);
      }
      __syncthreads();
      float acc = bg;
      acc = dot8f(P.wsG[0 * NRG + grow], zbn[0], acc);
      acc = dot8f(P.wsG[1 * NRG + grow], zbn[1], acc);
#pragma unroll 8
      for (int q = 18; q < 34; ++q)
        acc = dot8f(P.wsG[q * NRG + grow], zbn[q], acc);
      if (tid < 128) {
        unsigned short v16 = axpoll(EX + 128 + tid, t + 1);
        st16(zbn, 16 + tid, v16);
      }
      __syncthreads();
#pragma unroll 8
      for (int q = 2; q < 18; ++q) acc = dot8f(P.wsG[q * NRG + grow], zbn[q], acc);
      sm.garr[tid] = acc;
      __syncthreads();
      uint4* tmp = zbc; zbc = zbn; zbn = tmp;
    }
  } else {
    SMB& sm = *(SMB*)smraw;
    for (int i = tid; i < Q2LDS * NR2; i += 512) sm.l2w[i] = P.wsL2[i];
    for (int i = tid; i < NR2; i += 512) sm.cb2[i] = P.b2[i >> 7][i & 127];
    for (int i = tid; i < 768; i += 512) {
      int r = i >> 6, w = i & 63;
      const float* W = (r < 3) ? P.gW + r * 128 : (r < 6) ? P.aW + (r - 3) * 128 : P.uW + (r - 6) * 128;
      ((uint32_t*)sm.hwq)[i] = pk2(W[2 * w], W[2 * w + 1]);
    }
    if (tid < 12) sm.hb[tid] = (tid < 3) ? P.gb[tid] : (tid < 6) ? P.ab[tid - 3] : P.ub[tid - 6];
    {
      uint32_t* zz = (uint32_t*)sm.zb;
      for (int i = tid; i < (2 * QG + Q2) * 4; i += 512) zz[i] = 0u;
    }
    const int grow = ((tid >> 7) << 8) | 128 | (tid & 127);
    const float bg = P.bih[grow] + P.bhh[grow];
    float c_r = 0.f;
    __syncthreads();
    if (tid < 13) st16(sm.zb[0], tid, f16b(xb[tid]));
    __syncthreads();
    uint4* zbc = sm.zb[0];
    uint4* zbn = sm.zb[1];

    for (int t = 0; t < T_; ++t) {
      float acc = bg;
#pragma unroll 8
      for (int q = 0; q < QG; ++q)
        acc = dot8f(P.wsG[q * NRG + grow], zbc[q], acc);
      if (tid < 12 && t > 0) {
        int r = tid;
        float a = sm.hb[r];
#pragma unroll
        for (int q = 0; q < 16; ++q) a = dot8f(sm.hwq[r][q], zbc[2 + q], a);
        size_t base = ((size_t)b * T_ + (t - 1)) * 6;
        if (r < 6) P.out[base + r] = a;
        else {
          float sp = (a > 0.f) ? (a + log1pf(expf(-a))) : log1pf(expf(a));
          P.out[UNC_OFF + base + (r - 6)] = sp;
        }
      }
      sm.garr[tid] = acc;
      __syncthreads();
      if (tid < 128) {
        float gi = sm.garr[tid], gf = sm.garr[128 + tid];
        float gg = sm.garr[256 + tid], go = sm.garr[384 + tid];
        float cn = sigf(gf) * c_r + sigf(gi) * tanhf(gg);
        c_r = cn;
        float h = sigf(go) * tanhf(cn);
        st16(sm.z2, 56 + tid, f16b(h));
      } else if (tid >= 192 && tid < 208) {
        int i = tid - 192;
        if (i < 13) {
          float xv = (t + 1 < T_) ? xb[(size_t)(t + 1) * DIN + i] : 0.f;
          st16(zbn, i, f16b(xv));
        }
      }
      __syncthreads();
      float a2 = sm.cb2[tid];
#pragma unroll
      for (int q = 7; q < Q2LDS; ++q) a2 = dot8f(sm.l2w[q * NR2 + tid], sm.z2[q], a2);
#pragma unroll
      for (int q = Q2LDS; q < Q2; ++q) a2 = dot8f(P.wsL2[q * NR2 + tid], sm.z2[q], a2);
      if (tid < 128) {
        unsigned short v16 = axpoll(EX + tid, t + 1);
        if (tid < N0) {
          st16(zbn, 195 + tid, v16);
        } else {
          int j = tid - N0;
          st16(sm.z2, j, v16);
          st16(zbn, 144 + j, v16);
        }
      }
      __syncthreads();
#pragma unroll
      for (int q = 0; q < 7; ++q) a2 = dot8f(sm.l2w[q * NR2 + tid], sm.z2[q], a2);
      sm.ffb[tid] = (tid < 2 * N2) ? tanhf(a2) : a2;
      __syncthreads();
      if (tid < N2) {
        float ti = sigf(sm.ffb[2 * N2 + tid] + sm.ffb[3 * N2 + tid]);
        float v = sm.ffb[tid] * (1.f - ti) + ti * sm.ffb[N2 + tid];
        unsigned short v16 = f16b(v);
        axpub(EX + 128 + tid, t + 1, v16);
        st16(zbn, 16 + tid, v16);
      }
      __syncthreads();
      uint4* tmp = zbc; zbc = zbn; zbn = tmp;
    }
    if (tid < 12) {
      int r = tid;
      float a = sm.hb[r];
#pragma unroll
      for (int q = 0; q < 16; ++q) a = dot8f(sm.hwq[r][q], zbc[2 + q], a);
      size_t base = ((size_t)b * T_ + (T_ - 1)) * 6;
      if (r < 6) P.out[base + r] = a;
      else {
        float sp = (a > 0.f) ? (a + log1pf(expf(-a))) : log1pf(expf(a));
        P.out[UNC_OFF + base + (r - 6)] = sp;
      }
    }
  }
}

// ================= fallback: direct f32 kernel (no workspace) =================

struct Args {
  const float* x;
  const float* Wih; const float* Whh; const float* bih; const float* bhh;
  const float* W0[4]; const float* b0[4]; const float* m0;
  const float* W1[4]; const float* b1[4]; const float* m1;
  const float* W2[4]; const float* b2[4]; const float* m2;
  const float* gW; const float* gb; const float* aW; const float* ab;
  const float* uW; const float* ub;
  float* out;
};

struct SMF {
  float xt[16];
  float lstm_h[HS];
  float hprev[HS];
  float garr[4 * HS];
  float ffb[4][128];
  float cb0[NR0];
  float cb1[NR1];
  float cb2[NR2];
  float hw[12][132];
  float hb[12];
};

__global__ __launch_bounds__(512, 2) void rnn_fallback(Args A) {
  extern __shared__ char smraw[];
  SMF& sm = *(SMF*)smraw;
  const int tid = threadIdx.x;
  const int b = blockIdx.x;

  for (int i = tid; i < NR0; i += 512) sm.cb0[i] = A.b0[i / N0][i % N0];
  for (int i = tid; i < NR1; i += 512) sm.cb1[i] = A.b1[i / N1][i % N1];
  for (int i = tid; i < NR2; i += 512) sm.cb2[i] = A.b2[i / N2][i % N2];
  for (int i = tid; i < 12 * 128; i += 512) {
    int r = i >> 7, k = i & 127;
    sm.hw[r][k] = (r < 3) ? A.gW[r * 128 + k]
                : (r < 6) ? A.aW[(r - 3) * 128 + k]
                          : A.uW[(r - 6) * 128 + k];
  }
  if (tid < 12) sm.hb[tid] = (tid < 3) ? A.gb[tid] : (tid < 6) ? A.ab[tid - 3] : A.ub[tid - 6];
  for (int i = tid; i < HS; i += 512) sm.hprev[i] = 0.f;
  float bga = A.bih[tid] + A.bhh[tid];
  float bgb = A.bih[tid + 512] + A.bhh[tid + 512];
  float c_r = 0.f;
  __syncthreads();

  const float* xb = A.x + (size_t)b * T_ * DIN;
  const size_t UNC_OFF = (size_t)B_ * T_ * 6;

  for (int t = 0; t < T_; ++t) {
    const float* xp = xb + (size_t)t * DIN;
    if (tid < DIN) sm.xt[tid] = xp[tid];
    __syncthreads();

    float aa = bga, ab = bgb;
    for (int k = 0; k < DIN; ++k) {
      float xv = sm.xt[k];
      aa += A.Wih[tid * DIN + k] * xv;
      ab += A.Wih[(tid + 512) * DIN + k] * xv;
    }
    for (int k = 0; k < HS; ++k) {
      float hv = sm.hprev[k];
      aa += A.Whh[tid * HS + k] * hv;
      ab += A.Whh[(tid + 512) * HS + k] * hv;
    }
    sm.garr[tid] = aa;
    sm.garr[tid + 512] = ab;
    __syncthreads();

    if (tid < HS) {
      float gi = sm.garr[tid], gf = sm.garr[HS + tid];
      float gg = sm.garr[2 * HS + tid], go = sm.garr[3 * HS + tid];
      float cn = sigf(gf) * c_r + sigf(gi) * tanhf(gg);
      c_r = cn;
      sm.lstm_h[tid] = sigf(go) * tanhf(cn);
    }
    __syncthreads();

    if (tid < NR0) {
      int mat = tid / N0, o = tid % N0;
      const float* W = A.W0[mat];
      const float* m = A.m0;
      const int Kl = DIN + N0;
      float acc = sm.cb0[tid];
      for (int k = 0; k < DIN; ++k) {
        float w = W[o * Kl + k];
        if (mat < 2) w *= m[o * Kl + k];
        acc += w * sm.xt[k];
      }
      for (int k = DIN; k < Kl; ++k) acc += W[o * Kl + k] * sm.lstm_h[k - DIN];
      sm.ffb[mat][o] = (mat < 2) ? tanhf(acc) : acc;
    }
    __syncthreads();
    if (tid < N0) {
      float ti = sigf(sm.ffb[2][tid] + sm.ffb[3][tid]);
      sm.hprev[tid] = sm.ffb[0][tid] * (1.f - ti) + ti * sm.ffb[1][tid];
    }
    __syncthreads();

    if (tid < NR1) {
      int mat = tid / N1, o = tid % N1;
      const float* W = A.W1[mat];
      const float* m = A.m1;
      const int Kl = N0 + N1;
      float acc = sm.cb1[tid];
      for (int k = 0; k < N0; ++k) {
        float w = W[o * Kl + k];
        if (mat < 2) w *= m[o * Kl + k];
        acc += w * sm.hprev[k];
      }
      for (int k = N0; k < Kl; ++k) acc += W[o * Kl + k] * sm.lstm_h[k];
      sm.ffb[mat][o] = (mat < 2) ? tanhf(acc) : acc;
    }
    __syncthreads();
    if (tid < N1) {
      float ti = sigf(sm.ffb[2][tid] + sm.ffb[3][tid]);
      sm.hprev[N0 + tid] = sm.ffb[0][tid] * (1.f - ti) + ti * sm.ffb[1][tid];
    }
    __syncthreads();

    {
      int mat = tid >> 7, o = tid & 127;
      const float* W = A.W2[mat];
      const float* m = A.m2;
      const int Kl = N1 + N2;
      float acc = sm.cb2[tid];
      for (int k = 0; k < N1; ++k) {
        float w = W[o * Kl + k];
        if (mat < 2) w *= m[o * Kl + k];
        acc += w * sm.hprev[N0 + k];
      }
      for (int k = N1; k < Kl; ++k) acc += W[o * Kl + k] * sm.lstm_h[N0 + k];
      sm.ffb[mat][o] = (mat < 2) ? tanhf(acc) : acc;
    }
    __syncthreads();
    if (tid < N2) {
      float ti = sigf(sm.ffb[2][tid] + sm.ffb[3][tid]);
      sm.hprev[N0 + N1 + tid] = sm.ffb[0][tid] * (1.f - ti) + ti * sm.ffb[1][tid];
    }
    __syncthreads();

    if (tid >= 256 && tid < 268) {
      int r = tid - 256;
      const float* mo = &sm.hprev[N0 + N1];
      float acc = sm.hb[r];
      for (int k = 0; k < 128; ++k) acc += sm.hw[r][k] * mo[k];
      size_t base = ((size_t)b * T_ + t) * 6;
      if (r < 6) A.out[base + r] = acc;
      else {
        float sp = (acc > 0.f) ? (acc + log1pf(expf(-acc))) : log1pf(expf(acc));
        A.out[UNC_OFF + base + (r - 6)] = sp;
      }
    }
    __syncthreads();
  }
}

// ---------------- launcher ----------------

extern "C" void kernel_launch(void* const* d_in, const int* in_sizes, int n_in,
                              void* d_out, int out_size, void* d_ws, size_t ws_size,
                              hipStream_t stream) {
  const float* x   = (const float*)d_in[0];
  const float* Wih = (const float*)d_in[1];
  const float* Whh = (const float*)d_in[2];
  const float* bih = (const float*)d_in[3];
  const float* bhh = (const float*)d_in[4];
  const float *W[3][4], *bb[3][4], *mk[3];
  for (int l = 0; l < 3; ++l) {
    int base = 5 + l * 9;
    for (int nm = 0; nm < 4; ++nm) {
      W[l][nm]  = (const float*)d_in[base + 2 * nm];
      bb[l][nm] = (const float*)d_in[base + 2 * nm + 1];
    }
    mk[l] = (const float*)d_in[base + 8];
  }
  const float* gW = (const float*)d_in[32];
  const float* gb = (const float*)d_in[33];
  const float* aW = (const float*)d_in[34];
  const float* ab = (const float*)d_in[35];
  const float* uW = (const float*)d_in[36];
  const float* ub = (const float*)d_in[37];

  char* ws = (char*)d_ws;
  const size_t szG  = (size_t)QG * NRG * 16;   // 557056
  const size_t szL0 = (size_t)Q0 * NR0 * 16;   // 59136
  const size_t szL1 = (size_t)Q1 * NR1 * 16;   // 52224
  const size_t szL2 = (size_t)Q2 * NR2 * 16;   // 188416
  const size_t offG = 0, offL0 = szG, offL1 = offL0 + szL0, offL2 = offL1 + szL1;
  const size_t offEx = offL2 + szL2;           // 856832
  const size_t exBytes = 131072;               // 64 pairs x 512 ints (== 128 x 256)
  const size_t need = offEx + exBytes;         // 987904

  if (ws_size >= need) {
    PArgs P;
    P.x = x; P.bih = bih; P.bhh = bhh;
    for (int nm = 0; nm < 4; ++nm) { P.b0[nm] = bb[0][nm]; P.b1[nm] = bb[1][nm]; P.b2[nm] = bb[2][nm]; }
    P.gW = gW; P.gb = gb; P.aW = aW; P.ab = ab; P.uW = uW; P.ub = ub;
    P.wsG  = (const uint4*)(ws + offG);
    P.wsL0 = (const uint4*)(ws + offL0);
    P.wsL1 = (const uint4*)(ws + offL1);
    P.wsL2 = (const uint4*)(ws + offL2);
    P.ex   = (int*)(ws + offEx);
    P.out  = (float*)d_out;

    hipMemsetAsync(ws + offEx, 0, exBytes, stream);   // reset tags each launch/replay
    int n;
    n = 136 * NRG;
    prep_gates3<<<(n + 255) / 256, 256, 0, stream>>>(Wih, Whh, (uint32_t*)(ws + offG));
    n = NR0 * 48;
    prep_cfc2<<<(n + 255) / 256, 256, 0, stream>>>(W[0][0], W[0][1], W[0][2], W[0][3], mk[0],
                                                   N0, DIN + N0, NR0, 48,
                                                   90, 0, 96, 0, 0,
                                                   (uint32_t*)(ws + offL0));
    n = NR1 * 64;
    prep_cfc2<<<(n + 255) / 256, 256, 0, stream>>>(W[1][0], W[1][1], W[1][2], W[1][3], mk[1],
                                                   N1, N0 + N1, NR1, 64,
                                                   51, 77, 51, 77, 0,
                                                   (uint32_t*)(ws + offL1));
    n = NR2 * 92;
    prep_cfc2<<<(n + 255) / 256, 256, 0, stream>>>(W[2][0], W[2][1], W[2][2], W[2][3], mk[2],
                                                   N2, N1 + N2, NR2, 92,
                                                   51, 0, 56, 128, 51,
                                                   (uint32_t*)(ws + offL2));

    // G=2 kernel only if spill-free at the 128-VGPR cap; else proven coop3.
    hipFuncAttributes fa{};
    bool useG2 = false;
    if (hipFuncGetAttributes(&fa, reinterpret_cast<const void*>(&rnn_g2)) == hipSuccess) {
      useG2 = (fa.localSizeBytes == 0);
    }
    if (useG2) {
      int lds = (int)sizeof(SMB2);
      hipFuncSetAttribute(reinterpret_cast<const void*>(&rnn_g2),
                          hipFuncAttributeMaxDynamicSharedMemorySize, lds);
      rnn_g2<<<2 * NPAIR, 512, lds, stream>>>(P);
    } else {
      int lds = (int)((sizeof(SMA) > sizeof(SMB)) ? sizeof(SMA) : sizeof(SMB));
      hipFuncSetAttribute(reinterpret_cast<const void*>(&rnn_coop3),
                          hipFuncAttributeMaxDynamicSharedMemorySize, lds);
      rnn_coop3<<<2 * B_, 512, lds, stream>>>(P);
    }
    return;
  }

  // -------- fallback: direct f32 --------
  Args A;
  A.x = x; A.Wih = Wih; A.Whh = Whh; A.bih = bih; A.bhh = bhh;
  for (int nm = 0; nm < 4; ++nm) {
    A.W0[nm] = W[0][nm]; A.b0[nm] = bb[0][nm];
    A.W1[nm] = W[1][nm]; A.b1[nm] = bb[1][nm];
    A.W2[nm] = W[2][nm]; A.b2[nm] = bb[2][nm];
  }
  A.m0 = mk[0]; A.m1 = mk[1]; A.m2 = mk[2];
  A.gW = gW; A.gb = gb; A.aW = aW; A.ab = ab; A.uW = uW; A.ub = ub;
  A.out = (float*)d_out;
  hipFuncSetAttribute(reinterpret_cast<const void*>(&rnn_fallback),
                      hipFuncAttributeMaxDynamicSharedMemorySize, (int)sizeof(SMF));
  rnn_fallback<<<B_, 512, sizeof(SMF), stream>>>(A);
}

// Round 12
// 4803.153 us; speedup vs baseline: 1.4658x; 1.4658x over previous
//
#include <hip/hip_runtime.h>
#include <cstdint>

#define B_  128
#define T_  1024
#define DIN 13
#define HS  256
#define N0  77
#define N1  51
#define N2  128

// zg layout (f16 elems, 272 = 34 quads):
//   e0..12 x (13..15 pad) | e16..143 l2o | e144..194 l1o | e195..271 l0o
#define QG   34
#define NRG  1024
#define Q0   12
#define NR0  308
#define Q1   16
#define NR1  204
#define Q2   23
#define NR2  512
#define Q2LDS 18

// exchange (per b, stride 256 ints). Each word = (tag<<16) | f16bits.
#define EXSTRIDE 256

typedef _Float16 h2_t __attribute__((ext_vector_type(2)));

static __device__ __forceinline__ uint32_t pk2(float a, float b) {
  h2_t v; v.x = (_Float16)a; v.y = (_Float16)b;
  return __builtin_bit_cast(uint32_t, v);
}
static __device__ __forceinline__ unsigned short f16b(float v) {
  return __builtin_bit_cast(unsigned short, (_Float16)v);
}
static __device__ __forceinline__ void st16(void* base, int idx, unsigned short v) {
  ((unsigned short*)base)[idx] = v;
}
static __device__ __forceinline__ float dot2f(uint32_t w, uint32_t z, float acc) {
#if __has_builtin(__builtin_amdgcn_fdot2)
  return __builtin_amdgcn_fdot2(__builtin_bit_cast(h2_t, w), __builtin_bit_cast(h2_t, z), acc, false);
#else
  h2_t a = __builtin_bit_cast(h2_t, w), b = __builtin_bit_cast(h2_t, z);
  return acc + (float)a.x * (float)b.x + (float)a.y * (float)b.y;
#endif
}
static __device__ __forceinline__ float dot8f(uint4 w, uint4 z, float acc) {
  acc = dot2f(w.x, z.x, acc);
  acc = dot2f(w.y, z.y, acc);
  acc = dot2f(w.z, z.z, acc);
  acc = dot2f(w.w, z.w, acc);
  return acc;
}
static __device__ __forceinline__ float sigf(float x) { return 1.f / (1.f + expf(-x)); }

// tagged-word exchange: relaxed agent-scope atomics (coherent, no L2 invalidation).
// One word carries both "ready" (tag == t+1) and the f16 payload -> one L2/L3
// round trip per hop. Monotonic tags make it race-free; tags re-zeroed per launch.
static __device__ __forceinline__ void axpub(int* p, int tag, unsigned short v16) {
  __hip_atomic_store(p, (tag << 16) | (int)v16, __ATOMIC_RELAXED, __HIP_MEMORY_SCOPE_AGENT);
}
static __device__ __forceinline__ unsigned short axpoll(const int* p, int tag) {
  int w;
  do {
    w = __hip_atomic_load((int*)p, __ATOMIC_RELAXED, __HIP_MEMORY_SCOPE_AGENT);
  } while (((unsigned)w >> 16) != (unsigned)tag);
  return (unsigned short)(w & 0xFFFF);
}

// ---------------- prep kernels ----------------

__global__ void prep_gates3(const float* __restrict__ Wih, const float* __restrict__ Whh,
                            uint32_t* __restrict__ out) {
  int id = blockIdx.x * blockDim.x + threadIdx.x;
  if (id >= 136 * NRG) return;
  int k2 = id >> 10, row = id & (NRG - 1);
  float v[2];
#pragma unroll
  for (int j = 0; j < 2; ++j) {
    int e = 2 * k2 + j;
    float val = 0.f;
    if (e < 13) val = Wih[row * DIN + e];
    else if (e >= 16 && e < 144) val = Whh[row * HS + 128 + (e - 16)];
    else if (e >= 144 && e < 195) val = Whh[row * HS + 77 + (e - 144)];
    else if (e >= 195 && e < 272) val = Whh[row * HS + (e - 195)];
    v[j] = val;
  }
  out[((k2 >> 2) * NRG + row) * 4 + (k2 & 3)] = pk2(v[0], v[1]);
}

__global__ void prep_cfc2(const float* __restrict__ Wf1, const float* __restrict__ Wf2,
                          const float* __restrict__ Wta, const float* __restrict__ Wtb,
                          const float* __restrict__ mask,
                          int nh, int K, int NR, int K2,
                          int p0n, int p0c, int p1s, int p1n, int p1c,
                          uint32_t* __restrict__ out) {
  int id = blockIdx.x * blockDim.x + threadIdx.x;
  if (id >= NR * K2) return;
  int k2 = id / NR, r = id % NR;
  int mat = r / nh, o = r % nh;
  const float* W = (mat == 0) ? Wf1 : (mat == 1) ? Wf2 : (mat == 2) ? Wta : Wtb;
  float v[2];
#pragma unroll
  for (int j = 0; j < 2; ++j) {
    int e = 2 * k2 + j;
    int col = -1;
    if (e < p0n) col = p0c + e;
    else if (e >= p1s && e < p1s + p1n) col = p1c + (e - p1s);
    float val = 0.f;
    if (col >= 0) {
      val = W[o * K + col];
      if (mat < 2) val *= mask[o * K + col];
    }
    v[j] = val;
  }
  out[((k2 >> 2) * NR + r) * 4 + (k2 & 3)] = pk2(v[0], v[1]);
}

// ---------------- shared structs ----------------

struct SMA {
  uint4 l0w[Q0 * NR0];
  uint4 l1w[Q1 * NR1];
  uint4 zb[2][QG];
  uint4 z0[Q0];
  uint4 z1[Q1];
  float garr[512];
  float ffb[NR0];
  float cb0[NR0];
  float cb1[NR1];
};
struct SMB {
  uint4 l2w[Q2LDS * NR2];
  uint4 zb[2][QG];
  uint4 z2[Q2];
  float garr[512];
  float ffb[NR2];
  float cb2[NR2];
  uint4 hwq[12][16];
  float hb[12];
};
static_assert(sizeof(SMA) <= 163840, "SMA too big");
static_assert(sizeof(SMB) <= 163840, "SMB too big");

struct PArgs {
  const float* x;
  const float* bih; const float* bhh;
  const float* b0[4]; const float* b1[4]; const float* b2[4];
  const float* gW; const float* gb; const float* aW; const float* ab;
  const float* uW; const float* ub;
  const uint4* wsG; const uint4* wsL0; const uint4* wsL1; const uint4* wsL2;
  int* ex;
  float* out;
};

// ======== coop3: best-known configuration (96 VGPR, ~5.15 ms/dispatch) ========
// Pair-split (A: LSTM[0:128]+l0+l1; B: LSTM[128:256]+l2+heads), 2 fence-free
// tagged hops/step, CfC weights LDS-resident, gate matrix streamed from L2.
// Structural limit: serial recurrence chain + 2 cross-CU L2-latency hops +
// ~16 barrier phases per step. Register-stashing (128-VGPR toolchain cap),
// acquire/release fences (L2 invalidation), and G=2 batching (occupancy trade)
// all measured dead ends (rounds 2-11).
__global__ __launch_bounds__(512, 2) void rnn_coop3(PArgs P) {
  extern __shared__ char smraw[];
  const int tid = threadIdx.x;
  const bool isA = (blockIdx.x < B_);
  const int b = blockIdx.x & (B_ - 1);
  int* EX = P.ex + b * EXSTRIDE;
  const float* xb = P.x + (size_t)b * T_ * DIN;
  const size_t UNC_OFF = (size_t)B_ * T_ * 6;

  if (isA) {
    SMA& sm = *(SMA*)smraw;
    for (int i = tid; i < Q0 * NR0; i += 512) sm.l0w[i] = P.wsL0[i];
    for (int i = tid; i < Q1 * NR1; i += 512) sm.l1w[i] = P.wsL1[i];
    for (int i = tid; i < NR0; i += 512) sm.cb0[i] = P.b0[i / N0][i % N0];
    for (int i = tid; i < NR1; i += 512) sm.cb1[i] = P.b1[i / N1][i % N1];
    {
      uint32_t* zz = (uint32_t*)sm.zb;
      for (int i = tid; i < (2 * QG + Q0 + Q1) * 4; i += 512) zz[i] = 0u;
    }
    const int grow = ((tid >> 7) << 8) | (tid & 127);
    const float bg = P.bih[grow] + P.bhh[grow];
    float c_r = 0.f;
    __syncthreads();
    if (tid < 13) st16(sm.zb[0], tid, f16b(xb[tid]));
    __syncthreads();
    uint4* zbc = sm.zb[0];
    uint4* zbn = sm.zb[1];
    {
      float acc = bg;
      acc = dot8f(P.wsG[0 * NRG + grow], zbc[0], acc);
      acc = dot8f(P.wsG[1 * NRG + grow], zbc[1], acc);
      sm.garr[tid] = acc;
    }
    __syncthreads();

    for (int t = 0; t < T_; ++t) {
      if (tid < 128) {
        float gi = sm.garr[tid], gf = sm.garr[128 + tid];
        float gg = sm.garr[256 + tid], go = sm.garr[384 + tid];
        float cn = sigf(gf) * c_r + sigf(gi) * tanhf(gg);
        c_r = cn;
        float h = sigf(go) * tanhf(cn);
        if (tid < N0) st16(sm.z0, 13 + tid, f16b(h));
        else          st16(sm.z1, tid - N0, f16b(h));
      } else if (tid >= 320 && tid < 336) {
        int i = tid - 320;
        if (i < 13) {
          float xv = (t + 1 < T_) ? xb[(size_t)(t + 1) * DIN + i] : 0.f;
          st16(zbn, i, f16b(xv));
        }
      } else if (tid >= 336 && tid < 352) {
        int i = tid - 336;
        if (i < 13) st16(sm.z0, i, ((unsigned short*)zbc)[i]);
      }
      __syncthreads();
      if (tid < NR0) {
        float a = sm.cb0[tid];
#pragma unroll
        for (int q = 0; q < Q0; ++q) a = dot8f(sm.l0w[q * NR0 + tid], sm.z0[q], a);
        sm.ffb[tid] = (tid < 2 * N0) ? tanhf(a) : a;
      }
      __syncthreads();
      if (tid < N0) {
        float ti = sigf(sm.ffb[2 * N0 + tid] + sm.ffb[3 * N0 + tid]);
        float v = sm.ffb[tid] * (1.f - ti) + ti * sm.ffb[N0 + tid];
        unsigned short v16 = f16b(v);
        axpub(EX + tid, t + 1, v16);
        st16(sm.z1, 51 + tid, v16);
        st16(zbn, 195 + tid, v16);
      }
      __syncthreads();
      if (tid < NR1) {
        float a = sm.cb1[tid];
#pragma unroll
        for (int q = 0; q < Q1; ++q) a = dot8f(sm.l1w[q * NR1 + tid], sm.z1[q], a);
        sm.ffb[tid] = (tid < 2 * N1) ? tanhf(a) : a;
      }
      __syncthreads();
      if (tid < N1) {
        float ti = sigf(sm.ffb[2 * N1 + tid] + sm.ffb[3 * N1 + tid]);
        float v = sm.ffb[tid] * (1.f - ti) + ti * sm.ffb[N1 + tid];
        unsigned short v16 = f16b(v);
        axpub(EX + N0 + tid, t + 1, v16);
        st16(zbn, 144 + tid, v16);
      }
      __syncthreads();
      float acc = bg;
      acc = dot8f(P.wsG[0 * NRG + grow], zbn[0], acc);
      acc = dot8f(P.wsG[1 * NRG + grow], zbn[1], acc);
#pragma unroll 8
      for (int q = 18; q < 34; ++q)
        acc = dot8f(P.wsG[q * NRG + grow], zbn[q], acc);
      if (tid < 128) {
        unsigned short v16 = axpoll(EX + 128 + tid, t + 1);
        st16(zbn, 16 + tid, v16);
      }
      __syncthreads();
#pragma unroll 8
      for (int q = 2; q < 18; ++q) acc = dot8f(P.wsG[q * NRG + grow], zbn[q], acc);
      sm.garr[tid] = acc;
      __syncthreads();
      uint4* tmp = zbc; zbc = zbn; zbn = tmp;
    }
  } else {
    SMB& sm = *(SMB*)smraw;
    for (int i = tid; i < Q2LDS * NR2; i += 512) sm.l2w[i] = P.wsL2[i];
    for (int i = tid; i < NR2; i += 512) sm.cb2[i] = P.b2[i >> 7][i & 127];
    for (int i = tid; i < 768; i += 512) {
      int r = i >> 6, w = i & 63;
      const float* W = (r < 3) ? P.gW + r * 128 : (r < 6) ? P.aW + (r - 3) * 128 : P.uW + (r - 6) * 128;
      ((uint32_t*)sm.hwq)[i] = pk2(W[2 * w], W[2 * w + 1]);
    }
    if (tid < 12) sm.hb[tid] = (tid < 3) ? P.gb[tid] : (tid < 6) ? P.ab[tid - 3] : P.ub[tid - 6];
    {
      uint32_t* zz = (uint32_t*)sm.zb;
      for (int i = tid; i < (2 * QG + Q2) * 4; i += 512) zz[i] = 0u;
    }
    const int grow = ((tid >> 7) << 8) | 128 | (tid & 127);
    const float bg = P.bih[grow] + P.bhh[grow];
    float c_r = 0.f;
    __syncthreads();
    if (tid < 13) st16(sm.zb[0], tid, f16b(xb[tid]));
    __syncthreads();
    uint4* zbc = sm.zb[0];
    uint4* zbn = sm.zb[1];

    for (int t = 0; t < T_; ++t) {
      float acc = bg;
#pragma unroll 8
      for (int q = 0; q < QG; ++q)
        acc = dot8f(P.wsG[q * NRG + grow], zbc[q], acc);
      if (tid < 12 && t > 0) {
        int r = tid;
        float a = sm.hb[r];
#pragma unroll
        for (int q = 0; q < 16; ++q) a = dot8f(sm.hwq[r][q], zbc[2 + q], a);
        size_t base = ((size_t)b * T_ + (t - 1)) * 6;
        if (r < 6) P.out[base + r] = a;
        else {
          float sp = (a > 0.f) ? (a + log1pf(expf(-a))) : log1pf(expf(a));
          P.out[UNC_OFF + base + (r - 6)] = sp;
        }
      }
      sm.garr[tid] = acc;
      __syncthreads();
      if (tid < 128) {
        float gi = sm.garr[tid], gf = sm.garr[128 + tid];
        float gg = sm.garr[256 + tid], go = sm.garr[384 + tid];
        float cn = sigf(gf) * c_r + sigf(gi) * tanhf(gg);
        c_r = cn;
        float h = sigf(go) * tanhf(cn);
        st16(sm.z2, 56 + tid, f16b(h));
      } else if (tid >= 192 && tid < 208) {
        int i = tid - 192;
        if (i < 13) {
          float xv = (t + 1 < T_) ? xb[(size_t)(t + 1) * DIN + i] : 0.f;
          st16(zbn, i, f16b(xv));
        }
      }
      __syncthreads();
      float a2 = sm.cb2[tid];
#pragma unroll
      for (int q = 7; q < Q2LDS; ++q) a2 = dot8f(sm.l2w[q * NR2 + tid], sm.z2[q], a2);
#pragma unroll
      for (int q = Q2LDS; q < Q2; ++q) a2 = dot8f(P.wsL2[q * NR2 + tid], sm.z2[q], a2);
      if (tid < 128) {
        unsigned short v16 = axpoll(EX + tid, t + 1);
        if (tid < N0) {
          st16(zbn, 195 + tid, v16);
        } else {
          int j = tid - N0;
          st16(sm.z2, j, v16);
          st16(zbn, 144 + j, v16);
        }
      }
      __syncthreads();
#pragma unroll
      for (int q = 0; q < 7; ++q) a2 = dot8f(sm.l2w[q * NR2 + tid], sm.z2[q], a2);
      sm.ffb[tid] = (tid < 2 * N2) ? tanhf(a2) : a2;
      __syncthreads();
      if (tid < N2) {
        float ti = sigf(sm.ffb[2 * N2 + tid] + sm.ffb[3 * N2 + tid]);
        float v = sm.ffb[tid] * (1.f - ti) + ti * sm.ffb[N2 + tid];
        unsigned short v16 = f16b(v);
        axpub(EX + 128 + tid, t + 1, v16);
        st16(zbn, 16 + tid, v16);
      }
      __syncthreads();
      uint4* tmp = zbc; zbc = zbn; zbn = tmp;
    }
    if (tid < 12) {
      int r = tid;
      float a = sm.hb[r];
#pragma unroll
      for (int q = 0; q < 16; ++q) a = dot8f(sm.hwq[r][q], zbc[2 + q], a);
      size_t base = ((size_t)b * T_ + (T_ - 1)) * 6;
      if (r < 6) P.out[base + r] = a;
      else {
        float sp = (a > 0.f) ? (a + log1pf(expf(-a))) : log1pf(expf(a));
        P.out[UNC_OFF + base + (r - 6)] = sp;
      }
    }
  }
}

// ================= fallback: direct f32 kernel (no workspace) =================

struct Args {
  const float* x;
  const float* Wih; const float* Whh; const float* bih; const float* bhh;
  const float* W0[4]; const float* b0[4]; const float* m0;
  const float* W1[4]; const float* b1[4]; const float* m1;
  const float* W2[4]; const float* b2[4]; const float* m2;
  const float* gW; const float* gb; const float* aW; const float* ab;
  const float* uW; const float* ub;
  float* out;
};

struct SMF {
  float xt[16];
  float lstm_h[HS];
  float hprev[HS];
  float garr[4 * HS];
  float ffb[4][128];
  float cb0[NR0];
  float cb1[NR1];
  float cb2[NR2];
  float hw[12][132];
  float hb[12];
};

__global__ __launch_bounds__(512, 2) void rnn_fallback(Args A) {
  extern __shared__ char smraw[];
  SMF& sm = *(SMF*)smraw;
  const int tid = threadIdx.x;
  const int b = blockIdx.x;

  for (int i = tid; i < NR0; i += 512) sm.cb0[i] = A.b0[i / N0][i % N0];
  for (int i = tid; i < NR1; i += 512) sm.cb1[i] = A.b1[i / N1][i % N1];
  for (int i = tid; i < NR2; i += 512) sm.cb2[i] = A.b2[i / N2][i % N2];
  for (int i = tid; i < 12 * 128; i += 512) {
    int r = i >> 7, k = i & 127;
    sm.hw[r][k] = (r < 3) ? A.gW[r * 128 + k]
                : (r < 6) ? A.aW[(r - 3) * 128 + k]
                          : A.uW[(r - 6) * 128 + k];
  }
  if (tid < 12) sm.hb[tid] = (tid < 3) ? A.gb[tid] : (tid < 6) ? A.ab[tid - 3] : A.ub[tid - 6];
  for (int i = tid; i < HS; i += 512) sm.hprev[i] = 0.f;
  float bga = A.bih[tid] + A.bhh[tid];
  float bgb = A.bih[tid + 512] + A.bhh[tid + 512];
  float c_r = 0.f;
  __syncthreads();

  const float* xb = A.x + (size_t)b * T_ * DIN;
  const size_t UNC_OFF = (size_t)B_ * T_ * 6;

  for (int t = 0; t < T_; ++t) {
    const float* xp = xb + (size_t)t * DIN;
    if (tid < DIN) sm.xt[tid] = xp[tid];
    __syncthreads();

    float aa = bga, ab = bgb;
    for (int k = 0; k < DIN; ++k) {
      float xv = sm.xt[k];
      aa += A.Wih[tid * DIN + k] * xv;
      ab += A.Wih[(tid + 512) * DIN + k] * xv;
    }
    for (int k = 0; k < HS; ++k) {
      float hv = sm.hprev[k];
      aa += A.Whh[tid * HS + k] * hv;
      ab += A.Whh[(tid + 512) * HS + k] * hv;
    }
    sm.garr[tid] = aa;
    sm.garr[tid + 512] = ab;
    __syncthreads();

    if (tid < HS) {
      float gi = sm.garr[tid], gf = sm.garr[HS + tid];
      float gg = sm.garr[2 * HS + tid], go = sm.garr[3 * HS + tid];
      float cn = sigf(gf) * c_r + sigf(gi) * tanhf(gg);
      c_r = cn;
      sm.lstm_h[tid] = sigf(go) * tanhf(cn);
    }
    __syncthreads();

    if (tid < NR0) {
      int mat = tid / N0, o = tid % N0;
      const float* W = A.W0[mat];
      const float* m = A.m0;
      const int Kl = DIN + N0;
      float acc = sm.cb0[tid];
      for (int k = 0; k < DIN; ++k) {
        float w = W[o * Kl + k];
        if (mat < 2) w *= m[o * Kl + k];
        acc += w * sm.xt[k];
      }
      for (int k = DIN; k < Kl; ++k) acc += W[o * Kl + k] * sm.lstm_h[k - DIN];
      sm.ffb[mat][o] = (mat < 2) ? tanhf(acc) : acc;
    }
    __syncthreads();
    if (tid < N0) {
      float ti = sigf(sm.ffb[2][tid] + sm.ffb[3][tid]);
      sm.hprev[tid] = sm.ffb[0][tid] * (1.f - ti) + ti * sm.ffb[1][tid];
    }
    __syncthreads();

    if (tid < NR1) {
      int mat = tid / N1, o = tid % N1;
      const float* W = A.W1[mat];
      const float* m = A.m1;
      const int Kl = N0 + N1;
      float acc = sm.cb1[tid];
      for (int k = 0; k < N0; ++k) {
        float w = W[o * Kl + k];
        if (mat < 2) w *= m[o * Kl + k];
        acc += w * sm.hprev[k];
      }
      for (int k = N0; k < Kl; ++k) acc += W[o * Kl + k] * sm.lstm_h[k];
      sm.ffb[mat][o] = (mat < 2) ? tanhf(acc) : acc;
    }
    __syncthreads();
    if (tid < N1) {
      float ti = sigf(sm.ffb[2][tid] + sm.ffb[3][tid]);
      sm.hprev[N0 + tid] = sm.ffb[0][tid] * (1.f - ti) + ti * sm.ffb[1][tid];
    }
    __syncthreads();

    {
      int mat = tid >> 7, o = tid & 127;
      const float* W = A.W2[mat];
      const float* m = A.m2;
      const int Kl = N1 + N2;
      float acc = sm.cb2[tid];
      for (int k = 0; k < N1; ++k) {
        float w = W[o * Kl + k];
        if (mat < 2) w *= m[o * Kl + k];
        acc += w * sm.hprev[N0 + k];
      }
      for (int k = N1; k < Kl; ++k) acc += W[o * Kl + k] * sm.lstm_h[N0 + k];
      sm.ffb[mat][o] = (mat < 2) ? tanhf(acc) : acc;
    }
    __syncthreads();
    if (tid < N2) {
      float ti = sigf(sm.ffb[2][tid] + sm.ffb[3][tid]);
      sm.hprev[N0 + N1 + tid] = sm.ffb[0][tid] * (1.f - ti) + ti * sm.ffb[1][tid];
    }
    __syncthreads();

    if (tid >= 256 && tid < 268) {
      int r = tid - 256;
      const float* mo = &sm.hprev[N0 + N1];
      float acc = sm.hb[r];
      for (int k = 0; k < 128; ++k) acc += sm.hw[r][k] * mo[k];
      size_t base = ((size_t)b * T_ + t) * 6;
      if (r < 6) A.out[base + r] = acc;
      else {
        float sp = (acc > 0.f) ? (acc + log1pf(expf(-acc))) : log1pf(expf(acc));
        A.out[UNC_OFF + base + (r - 6)] = sp;
      }
    }
    __syncthreads();
  }
}

// ---------------- launcher ----------------

extern "C" void kernel_launch(void* const* d_in, const int* in_sizes, int n_in,
                              void* d_out, int out_size, void* d_ws, size_t ws_size,
                              hipStream_t stream) {
  const float* x   = (const float*)d_in[0];
  const float* Wih = (const float*)d_in[1];
  const float* Whh = (const float*)d_in[2];
  const float* bih = (const float*)d_in[3];
  const float* bhh = (const float*)d_in[4];
  const float *W[3][4], *bb[3][4], *mk[3];
  for (int l = 0; l < 3; ++l) {
    int base = 5 + l * 9;
    for (int nm = 0; nm < 4; ++nm) {
      W[l][nm]  = (const float*)d_in[base + 2 * nm];
      bb[l][nm] = (const float*)d_in[base + 2 * nm + 1];
    }
    mk[l] = (const float*)d_in[base + 8];
  }
  const float* gW = (const float*)d_in[32];
  const float* gb = (const float*)d_in[33];
  const float* aW = (const float*)d_in[34];
  const float* ab = (const float*)d_in[35];
  const float* uW = (const float*)d_in[36];
  const float* ub = (const float*)d_in[37];

  char* ws = (char*)d_ws;
  const size_t szG  = (size_t)QG * NRG * 16;   // 557056
  const size_t szL0 = (size_t)Q0 * NR0 * 16;   // 59136
  const size_t szL1 = (size_t)Q1 * NR1 * 16;   // 52224
  const size_t szL2 = (size_t)Q2 * NR2 * 16;   // 188416
  const size_t offG = 0, offL0 = szG, offL1 = offL0 + szL0, offL2 = offL1 + szL1;
  const size_t offEx = offL2 + szL2;           // 856832
  const size_t exBytes = (size_t)B_ * EXSTRIDE * 4;  // 131072
  const size_t need = offEx + exBytes;         // 987904

  if (ws_size >= need) {
    PArgs P;
    P.x = x; P.bih = bih; P.bhh = bhh;
    for (int nm = 0; nm < 4; ++nm) { P.b0[nm] = bb[0][nm]; P.b1[nm] = bb[1][nm]; P.b2[nm] = bb[2][nm]; }
    P.gW = gW; P.gb = gb; P.aW = aW; P.ab = ab; P.uW = uW; P.ub = ub;
    P.wsG  = (const uint4*)(ws + offG);
    P.wsL0 = (const uint4*)(ws + offL0);
    P.wsL1 = (const uint4*)(ws + offL1);
    P.wsL2 = (const uint4*)(ws + offL2);
    P.ex   = (int*)(ws + offEx);
    P.out  = (float*)d_out;

    hipMemsetAsync(ws + offEx, 0, exBytes, stream);   // reset tags each launch/replay
    int n;
    n = 136 * NRG;
    prep_gates3<<<(n + 255) / 256, 256, 0, stream>>>(Wih, Whh, (uint32_t*)(ws + offG));
    n = NR0 * 48;
    prep_cfc2<<<(n + 255) / 256, 256, 0, stream>>>(W[0][0], W[0][1], W[0][2], W[0][3], mk[0],
                                                   N0, DIN + N0, NR0, 48,
                                                   90, 0, 96, 0, 0,
                                                   (uint32_t*)(ws + offL0));
    n = NR1 * 64;
    prep_cfc2<<<(n + 255) / 256, 256, 0, stream>>>(W[1][0], W[1][1], W[1][2], W[1][3], mk[1],
                                                   N1, N0 + N1, NR1, 64,
                                                   51, 77, 51, 77, 0,
                                                   (uint32_t*)(ws + offL1));
    n = NR2 * 92;
    prep_cfc2<<<(n + 255) / 256, 256, 0, stream>>>(W[2][0], W[2][1], W[2][2], W[2][3], mk[2],
                                                   N2, N1 + N2, NR2, 92,
                                                   51, 0, 56, 128, 51,
                                                   (uint32_t*)(ws + offL2));
    int lds = (int)((sizeof(SMA) > sizeof(SMB)) ? sizeof(SMA) : sizeof(SMB));
    hipFuncSetAttribute(reinterpret_cast<const void*>(&rnn_coop3),
                        hipFuncAttributeMaxDynamicSharedMemorySize, lds);
    rnn_coop3<<<2 * B_, 512, lds, stream>>>(P);
    return;
  }

  // -------- fallback: direct f32 --------
  Args A;
  A.x = x; A.Wih = Wih; A.Whh = Whh; A.bih = bih; A.bhh = bhh;
  for (int nm = 0; nm < 4; ++nm) {
    A.W0[nm] = W[0][nm]; A.b0[nm] = bb[0][nm];
    A.W1[nm] = W[1][nm]; A.b1[nm] = bb[1][nm];
    A.W2[nm] = W[2][nm]; A.b2[nm] = bb[2][nm];
  }
  A.m0 = mk[0]; A.m1 = mk[1]; A.m2 = mk[2];
  A.gW = gW; A.gb = gb; A.aW = aW; A.ab = ab; A.uW = uW; A.ub = ub;
  A.out = (float*)d_out;
  hipFuncSetAttribute(reinterpret_cast<const void*>(&rnn_fallback),
                      hipFuncAttributeMaxDynamicSharedMemorySize, (int)sizeof(SMF));
  rnn_fallback<<<B_, 512, sizeof(SMF), stream>>>(A);
}